// Round 9
// baseline (106.325 us; speedup 1.0000x reference)
//
#include <hip/hip_runtime.h>
#include <hip/hip_cooperative_groups.h>

namespace cg = cooperative_groups;

#define F_IN 64
#define KHEADS 4

typedef float float4v __attribute__((ext_vector_type(4)));

// ---------------- shared device code (phase bodies) ----------------

__device__ __forceinline__ void proj_body(const float4v* __restrict__ x4,
                                          const float4v* __restrict__ att_s,
                                          float4v* __restrict__ ps4,
                                          float4v* __restrict__ pt4,
                                          int gid) {
    const int node = gid >> 3;
    const int sub  = gid & 7;
    // Coalesced + nontemporal (x is streamed exactly once)
    const float4v xv0 = __builtin_nontemporal_load(x4 + (size_t)node * 16 + sub);
    const float4v xv1 = __builtin_nontemporal_load(x4 + (size_t)node * 16 + 8 + sub);

    float acc[8];
    #pragma unroll
    for (int k = 0; k < KHEADS; ++k) {
        const float4v a0 = att_s[k * 32 + sub];
        const float4v a1 = att_s[k * 32 + 8 + sub];
        const float4v b0 = att_s[k * 32 + 16 + sub];
        const float4v b1 = att_s[k * 32 + 24 + sub];
        acc[k]          = xv0.x*a0.x + xv0.y*a0.y + xv0.z*a0.z + xv0.w*a0.w
                        + xv1.x*a1.x + xv1.y*a1.y + xv1.z*a1.z + xv1.w*a1.w;
        acc[KHEADS + k] = xv0.x*b0.x + xv0.y*b0.y + xv0.z*b0.z + xv0.w*b0.w
                        + xv1.x*b1.x + xv1.y*b1.y + xv1.z*b1.z + xv1.w*b1.w;
    }

    // Butterfly within the 8-lane group (masks 1,2,4 stay in-group)
    #pragma unroll
    for (int m = 1; m < 8; m <<= 1) {
        #pragma unroll
        for (int i = 0; i < 8; ++i) acc[i] += __shfl_xor(acc[i], m, 64);
    }

    if (sub == 0) {
        float4v lo; lo.x = acc[0]; lo.y = acc[1]; lo.z = acc[2]; lo.w = acc[3];
        ps4[node] = lo;
    } else if (sub == 1) {
        float4v hi; hi.x = acc[4]; hi.y = acc[5]; hi.z = acc[6]; hi.w = acc[7];
        pt4[node] = hi;
    }
}

__device__ __forceinline__ void edge_body(const int* __restrict__ sidx,
                                          const int* __restrict__ tidx,
                                          const float4v* __restrict__ ps4,
                                          const float4v* __restrict__ pt4,
                                          float4v* __restrict__ out4,
                                          int i, int n_pairs) {
    const int s0 = __builtin_nontemporal_load(sidx + i);
    const int t0 = __builtin_nontemporal_load(tidx + i);
    const int s1 = __builtin_nontemporal_load(sidx + i + n_pairs);
    const int t1 = __builtin_nontemporal_load(tidx + i + n_pairs);
    // CACHED gathers — tables are the hot, reused structure (round-6 lesson)
    const float4v ps0 = ps4[s0];
    const float4v pt0 = pt4[t0];
    const float4v ps1 = ps4[s1];
    const float4v pt1 = pt4[t1];
    float4v o0, o1;
    o0.x = fmaxf(ps0.x + pt0.x, 0.0f);
    o0.y = fmaxf(ps0.y + pt0.y, 0.0f);
    o0.z = fmaxf(ps0.z + pt0.z, 0.0f);
    o0.w = fmaxf(ps0.w + pt0.w, 0.0f);
    o1.x = fmaxf(ps1.x + pt1.x, 0.0f);
    o1.y = fmaxf(ps1.y + pt1.y, 0.0f);
    o1.z = fmaxf(ps1.z + pt1.z, 0.0f);
    o1.w = fmaxf(ps1.w + pt1.w, 0.0f);
    __builtin_nontemporal_store(o0, out4 + i);
    __builtin_nontemporal_store(o1, out4 + i + n_pairs);
}

// ---------------- fused cooperative kernel ----------------

__global__ __launch_bounds__(256, 2) void fused_kernel(
    const float4v* __restrict__ x4,
    const float4v* __restrict__ att4,
    const int*     __restrict__ sidx,
    const int*     __restrict__ tidx,
    float4v*       __restrict__ ps4,
    float4v*       __restrict__ pt4,
    float4v*       __restrict__ out4,
    int n_nodes, int n_pairs)
{
    __shared__ float4v att_s[128];
    if (threadIdx.x < 128) att_s[threadIdx.x] = att4[threadIdx.x];
    __syncthreads();

    const int nthreads = (int)(gridDim.x * blockDim.x);   // multiple of 8
    const int tid0     = (int)(blockIdx.x * blockDim.x + threadIdx.x);

    const int n_sub = n_nodes * 8;
    for (int gid = tid0; gid < n_sub; gid += nthreads)
        proj_body(x4, att_s, ps4, pt4, gid);

    // Cross-XCD visibility of the tables, then grid barrier.
    __threadfence();
    cg::this_grid().sync();

    for (int i = tid0; i < n_pairs; i += nthreads)
        edge_body(sidx, tidx, ps4, pt4, out4, i, n_pairs);
}

// ---------------- fallback 2-kernel path ----------------

__global__ __launch_bounds__(256) void proj_kernel(const float4v* __restrict__ x4,
                                                   const float4v* __restrict__ att4,
                                                   float4v* __restrict__ ps4,
                                                   float4v* __restrict__ pt4,
                                                   int n_nodes) {
    __shared__ float4v att_s[128];
    if (threadIdx.x < 128) att_s[threadIdx.x] = att4[threadIdx.x];
    __syncthreads();
    const int gid = (int)(blockIdx.x * blockDim.x + threadIdx.x);
    if (gid >= n_nodes * 8) return;
    proj_body(x4, att_s, ps4, pt4, gid);
}

__global__ __launch_bounds__(256) void edge_kernel(const int* __restrict__ sidx,
                                                   const int* __restrict__ tidx,
                                                   const float4v* __restrict__ ps4,
                                                   const float4v* __restrict__ pt4,
                                                   float4v* __restrict__ out4,
                                                   int n_pairs) {
    const int i = (int)(blockIdx.x * blockDim.x + threadIdx.x);
    if (i >= n_pairs) return;
    edge_body(sidx, tidx, ps4, pt4, out4, i, n_pairs);
}

extern "C" void kernel_launch(void* const* d_in, const int* in_sizes, int n_in,
                              void* d_out, int out_size, void* d_ws, size_t ws_size,
                              hipStream_t stream) {
    const float* x    = (const float*)d_in[0];
    const int*   eidx = (const int*)d_in[1];    // harness delivers integer inputs as int32
    const float* att  = (const float*)d_in[2];

    const int n_nodes = in_sizes[0] / F_IN;     // 50000
    const int n_edges = in_sizes[1] / 2;        // 800000 (even)
    const int n_pairs = n_edges / 2;            // 400000

    float4v* ps4 = (float4v*)d_ws;
    float4v* pt4 = (float4v*)((char*)d_ws + (size_t)n_nodes * 4 * sizeof(float));

    const float4v* x4   = (const float4v*)x;
    const float4v* att4 = (const float4v*)att;
    const int*     s0   = eidx;
    const int*     t0   = eidx + n_edges;
    float4v*       out4 = (float4v*)d_out;
    int nn = n_nodes, np = n_pairs;

    void* args[] = { (void*)&x4, (void*)&att4, (void*)&s0, (void*)&t0,
                     (void*)&ps4, (void*)&pt4, (void*)&out4, (void*)&nn, (void*)&np };

    // 512 blocks x 256 thr = 2 blocks/CU — comfortably under the cooperative
    // co-residency limit (round-7's 1024 was at the edge and got rejected).
    hipError_t err = hipLaunchCooperativeKernel((const void*)fused_kernel,
                                                dim3(512), dim3(256),
                                                args, 0, stream);
    if (err != hipSuccess) {
        // Fallback: proven 2-kernel path (never silently produce zeros).
        const int blocks1 = (n_nodes * 8 + 255) / 256;
        proj_kernel<<<blocks1, 256, 0, stream>>>(x4, att4, ps4, pt4, n_nodes);
        const int blocks2 = (n_pairs + 255) / 256;
        edge_kernel<<<blocks2, 256, 0, stream>>>(s0, t0, ps4, pt4, out4, n_pairs);
    }
}

// Round 10
// 20.742 us; speedup vs baseline: 5.1260x; 5.1260x over previous
//
#include <hip/hip_runtime.h>

#define F_IN 64
#define KHEADS 4

typedef float float4v __attribute__((ext_vector_type(4)));

// Kernel 1: 8 lanes per node, fully coalesced x reads.
// Lane sub (0..7) owns features [sub*4, sub*4+4) and [32+sub*4, 32+sub*4+4).
// 3-stage butterfly within each 8-lane group reduces the partial dots.
// p_src[node][k] = x[node].att[k][0:64], p_tgt[node][k] = x[node].att[k][64:128]
__global__ __launch_bounds__(256) void proj_kernel(const float4v* __restrict__ x4,
                                                   const float4v* __restrict__ att4,
                                                   float4v* __restrict__ ps4,
                                                   float4v* __restrict__ pt4,
                                                   int n_nodes) {
    __shared__ float4v att_s[128];             // 4 heads x 128 floats
    if (threadIdx.x < 128) att_s[threadIdx.x] = att4[threadIdx.x];
    __syncthreads();

    const int gid  = (int)(blockIdx.x * blockDim.x + threadIdx.x);
    const int node = gid >> 3;
    const int sub  = gid & 7;
    if (node >= n_nodes) return;

    // Coalesced + nontemporal (x is streamed exactly once)
    const float4v xv0 = __builtin_nontemporal_load(x4 + (size_t)node * 16 + sub);
    const float4v xv1 = __builtin_nontemporal_load(x4 + (size_t)node * 16 + 8 + sub);

    float acc[8];
    #pragma unroll
    for (int k = 0; k < KHEADS; ++k) {
        const float4v a0 = att_s[k * 32 + sub];
        const float4v a1 = att_s[k * 32 + 8 + sub];
        const float4v b0 = att_s[k * 32 + 16 + sub];
        const float4v b1 = att_s[k * 32 + 24 + sub];
        acc[k]          = xv0.x*a0.x + xv0.y*a0.y + xv0.z*a0.z + xv0.w*a0.w
                        + xv1.x*a1.x + xv1.y*a1.y + xv1.z*a1.z + xv1.w*a1.w;
        acc[KHEADS + k] = xv0.x*b0.x + xv0.y*b0.y + xv0.z*b0.z + xv0.w*b0.w
                        + xv1.x*b1.x + xv1.y*b1.y + xv1.z*b1.z + xv1.w*b1.w;
    }

    #pragma unroll
    for (int m = 1; m < 8; m <<= 1) {
        #pragma unroll
        for (int i = 0; i < 8; ++i) acc[i] += __shfl_xor(acc[i], m, 64);
    }

    if (sub == 0) {
        float4v lo; lo.x = acc[0]; lo.y = acc[1]; lo.z = acc[2]; lo.w = acc[3];
        ps4[node] = lo;
    } else if (sub == 1) {
        float4v hi; hi.x = acc[4]; hi.y = acc[5]; hi.z = acc[6]; hi.w = acc[7];
        pt4[node] = hi;
    }
}

// Kernel 2 (v5): 2 edges per thread; the 4 random gathers use sc0
// (L1-bypass, L2-served) loads via inline asm — avoids 64-128B L1 line-fill
// amplification on ~96%-miss random accesses while KEEPING the tables
// L2-resident (unlike nt, which de-cached them — round-6 regression).
// All 4 loads issued back-to-back, single vmcnt(0): MLP preserved.
__global__ __launch_bounds__(256) void edge_kernel(const int* __restrict__ sidx,
                                                   const int* __restrict__ tidx,
                                                   const float4v* __restrict__ ps4,
                                                   const float4v* __restrict__ pt4,
                                                   float4v* __restrict__ out4,
                                                   int n_pairs) {
    const int i = (int)(blockIdx.x * blockDim.x + threadIdx.x);
    if (i >= n_pairs) return;
    const int s0 = __builtin_nontemporal_load(sidx + i);
    const int t0 = __builtin_nontemporal_load(tidx + i);
    const int s1 = __builtin_nontemporal_load(sidx + i + n_pairs);
    const int t1 = __builtin_nontemporal_load(tidx + i + n_pairs);

    const float4v* a0 = ps4 + s0;
    const float4v* a1 = pt4 + t0;
    const float4v* a2 = ps4 + s1;
    const float4v* a3 = pt4 + t1;

    float4v ps0, pt0, ps1, pt1;
    asm volatile(
        "global_load_dwordx4 %0, %4, off sc0\n\t"
        "global_load_dwordx4 %1, %5, off sc0\n\t"
        "global_load_dwordx4 %2, %6, off sc0\n\t"
        "global_load_dwordx4 %3, %7, off sc0\n\t"
        "s_waitcnt vmcnt(0)"
        : "=&v"(ps0), "=&v"(pt0), "=&v"(ps1), "=&v"(pt1)
        : "v"(a0), "v"(a1), "v"(a2), "v"(a3));

    float4v o0, o1;
    o0.x = fmaxf(ps0.x + pt0.x, 0.0f);
    o0.y = fmaxf(ps0.y + pt0.y, 0.0f);
    o0.z = fmaxf(ps0.z + pt0.z, 0.0f);
    o0.w = fmaxf(ps0.w + pt0.w, 0.0f);
    o1.x = fmaxf(ps1.x + pt1.x, 0.0f);
    o1.y = fmaxf(ps1.y + pt1.y, 0.0f);
    o1.z = fmaxf(ps1.z + pt1.z, 0.0f);
    o1.w = fmaxf(ps1.w + pt1.w, 0.0f);
    __builtin_nontemporal_store(o0, out4 + i);
    __builtin_nontemporal_store(o1, out4 + i + n_pairs);
}

extern "C" void kernel_launch(void* const* d_in, const int* in_sizes, int n_in,
                              void* d_out, int out_size, void* d_ws, size_t ws_size,
                              hipStream_t stream) {
    const float* x    = (const float*)d_in[0];
    const int*   eidx = (const int*)d_in[1];    // harness delivers integer inputs as int32
    const float* att  = (const float*)d_in[2];
    float*       out  = (float*)d_out;

    const int n_nodes = in_sizes[0] / F_IN;     // 50000
    const int n_edges = in_sizes[1] / 2;        // 800000 (even)
    const int n_pairs = n_edges / 2;            // 400000

    // Split projection tables: 800 KB each, 16B-aligned.
    float4v* ps4 = (float4v*)d_ws;
    float4v* pt4 = (float4v*)((char*)d_ws + (size_t)n_nodes * 4 * sizeof(float));

    // Kernel 1: 8 threads per node
    const int threads1 = n_nodes * 8;
    const int blocks1  = (threads1 + 255) / 256;
    proj_kernel<<<blocks1, 256, 0, stream>>>((const float4v*)x, (const float4v*)att,
                                             ps4, pt4, n_nodes);

    // Kernel 2: 2 edges per thread
    const int blocks2 = (n_pairs + 255) / 256;
    edge_kernel<<<blocks2, 256, 0, stream>>>(eidx, eidx + n_edges,
                                             ps4, pt4, (float4v*)out, n_pairs);
}